// Round 1
// baseline (889.075 us; speedup 1.0000x reference)
//
#include <hip/hip_runtime.h>

typedef unsigned int uint;
typedef unsigned short ushort;
typedef __bf16 v8bf __attribute__((ext_vector_type(8)));
typedef float v4f __attribute__((ext_vector_type(4)));

#define CCH 256
#define HH 336
#define WW 336
#define HWSZ (HH*WW)
#define NROI 2000
#define KDIM 12544       // 49*256
#define MPAD 2048
#define SPLITK 14
#define KSP (KDIM/SPLITK)   // 896

__device__ __forceinline__ ushort bf16r(float f) {
  uint u = __float_as_uint(f);
  u += 0x7fffu + ((u >> 16) & 1u);   // RTNE
  return (ushort)(u >> 16);
}

typedef const __attribute__((address_space(1))) uint* gas_t;
typedef __attribute__((address_space(3))) uint* las_t;
__device__ __forceinline__ void async16(const void* g, void* l) {
  __builtin_amdgcn_global_load_lds((gas_t)g, (las_t)l, 16, 0, 0);
}

// features [256][336][336] fp32 -> ft [hw][c] bf16
__global__ __launch_bounds__(128) void k_transpose(const float* __restrict__ f,
                                                   ushort* __restrict__ ft) {
  int c8 = threadIdx.x & 31;      // channel-octet
  int hwo = threadIdx.x >> 5;     // 0..3
  int hw0 = blockIdx.x * 128;
  const float* fp = f + (size_t)c8 * 8 * HWSZ;
  for (int i = 0; i < 32; ++i) {
    int hw = hw0 + i * 4 + hwo;
    uint u[4];
#pragma unroll
    for (int j = 0; j < 4; ++j) {
      float a = fp[(size_t)(2 * j) * HWSZ + hw];
      float b = fp[(size_t)(2 * j + 1) * HWSZ + hw];
      u[j] = (uint)bf16r(a) | ((uint)bf16r(b) << 16);
    }
    *(uint4*)(ft + (size_t)hw * 256 + c8 * 8) = make_uint4(u[0], u[1], u[2], u[3]);
  }
}

// w1 [12544][256] fp32 (k = c*49+bin) -> w1t bf16 [n][k'] with k' = bin*256+c
__global__ __launch_bounds__(256) void k_w1perm(const float* __restrict__ w1,
                                                uint* __restrict__ w1t_u) {
  int bin = blockIdx.x % 49;
  int c0 = (blockIdx.x / 49) * 32;
  __shared__ ushort T[32][258];
  int n = threadIdx.x;
  for (int i = 0; i < 32; ++i)
    T[i][n] = bf16r(w1[(size_t)((c0 + i) * 49 + bin) * 256 + n]);
  __syncthreads();
  int cc = threadIdx.x & 15;
  int nb = threadIdx.x >> 4;
  for (int rep = 0; rep < 16; ++rep) {
    int nn = rep * 16 + nb;
    uint v = (uint)T[2 * cc][nn] | ((uint)T[2 * cc + 1][nn] << 16);
    w1t_u[(size_t)nn * (KDIM / 2) + bin * 128 + c0 / 2 + cc] = v;
  }
}

// w2 [256][256] -> w2t bf16 [n][k]
__global__ __launch_bounds__(256) void k_w2t(const float* __restrict__ w2,
                                             ushort* __restrict__ w2t) {
  int n = blockIdx.x, k = threadIdx.x;
  w2t[n * 256 + k] = bf16r(w2[k * 256 + n]);
}

// 1 block per ROI; 128 threads = channel pairs; rf[n][bin*256+c] bf16
__global__ __launch_bounds__(128) void k_pool(const int* __restrict__ rois,
                                              const uint* __restrict__ ftu,
                                              uint* __restrict__ rf_u) {
  int n = blockIdx.x;
  int c2 = threadIdx.x;
  int x1 = rois[n * 4 + 0], y1 = rois[n * 4 + 1];
  int x2 = rois[n * 4 + 2], y2 = rois[n * 4 + 3];
  int Lw = x2 - x1 + 1, Lh = y2 - y1 + 1;
  uint obase = (uint)n * (KDIM / 2);
  for (int by = 0; by < 7; ++by) {
    int ylo = y1 + (by * Lh) / 7;
    int yhi = y1 + ((by + 1) * Lh + 6) / 7;
    for (int bx = 0; bx < 7; ++bx) {
      int xlo = x1 + (bx * Lw) / 7;
      int xhi = x1 + ((bx + 1) * Lw + 6) / 7;
      float ax = 0.f, ay = 0.f;
      for (int y = ylo; y < yhi; ++y) {
        const uint* p = ftu + (size_t)(y * WW + xlo) * 128 + c2;
        for (int x = xlo; x < xhi; ++x) {
          uint u = *p; p += 128;
          ax += __uint_as_float(u << 16);
          ay += __uint_as_float(u & 0xffff0000u);
        }
      }
      float inv = 1.0f / (float)((yhi - ylo) * (xhi - xlo));
      uint v = (uint)bf16r(ax * inv) | ((uint)bf16r(ay * inv) << 16);
      rf_u[obase + (uint)(by * 7 + bx) * 128 + c2] = v;
    }
  }
}

// NT GEMM: A=rf [2048][12544], B=w1t [256][12544], split-K -> P [14][2048][256] fp32
__global__ __launch_bounds__(256) void k_gemm1(const ushort* __restrict__ A,
                                               const ushort* __restrict__ B,
                                               float* __restrict__ P) {
  __shared__ ushort As[128 * 64];
  __shared__ ushort Bs[128 * 64];
  int m0 = blockIdx.x * 128;
  int n0 = blockIdx.y * 128;
  int ks = blockIdx.z;
  int k0 = ks * KSP;
  int tid = threadIdx.x;
  int lane = tid & 63, wv = tid >> 6;
  int wm = wv >> 1, wn = wv & 1;
  int lm = lane & 15, quad = lane >> 4;
  int srow = tid >> 3, scol = (tid & 7) * 8;
  v4f acc[4][4];
#pragma unroll
  for (int i = 0; i < 4; ++i)
#pragma unroll
    for (int j = 0; j < 4; ++j) acc[i][j] = (v4f){0.f, 0.f, 0.f, 0.f};
  const ushort* Ab = A + (size_t)(m0 + srow) * KDIM + k0 + scol;
  const ushort* Bb = B + (size_t)(n0 + srow) * KDIM + k0 + scol;
  for (int kt = 0; kt < KSP / 64; ++kt) {
    __syncthreads();
#pragma unroll
    for (int r = 0; r < 4; ++r)
      async16(Ab + (size_t)(r * 32) * KDIM + kt * 64, &As[(srow + r * 32) * 64 + scol]);
#pragma unroll
    for (int r = 0; r < 4; ++r)
      async16(Bb + (size_t)(r * 32) * KDIM + kt * 64, &Bs[(srow + r * 32) * 64 + scol]);
    __syncthreads();
#pragma unroll
    for (int kk = 0; kk < 64; kk += 32) {
      v8bf a[4], b[4];
#pragma unroll
      for (int i = 0; i < 4; ++i)
        a[i] = *(const v8bf*)&As[(wm * 64 + i * 16 + lm) * 64 + kk + quad * 8];
#pragma unroll
      for (int j = 0; j < 4; ++j)
        b[j] = *(const v8bf*)&Bs[(wn * 64 + j * 16 + lm) * 64 + kk + quad * 8];
#pragma unroll
      for (int i = 0; i < 4; ++i)
#pragma unroll
        for (int j = 0; j < 4; ++j)
          acc[i][j] = __builtin_amdgcn_mfma_f32_16x16x32_bf16(a[i], b[j], acc[i][j], 0, 0, 0);
    }
  }
  float* Pb = P + (size_t)ks * MPAD * 256;
#pragma unroll
  for (int i = 0; i < 4; ++i)
#pragma unroll
    for (int j = 0; j < 4; ++j) {
      int row = m0 + wm * 64 + i * 16 + quad * 4;
      int col = n0 + wn * 64 + j * 16 + lm;
#pragma unroll
      for (int r = 0; r < 4; ++r)
        Pb[(size_t)(row + r) * 256 + col] = acc[i][j][r];
    }
}

// sum split-K partials + bias + relu -> h1 bf16 [2048][256]
__global__ __launch_bounds__(256) void k_reduce(const float* __restrict__ P,
                                                const float* __restrict__ b1,
                                                uint* __restrict__ h1u) {
  int idx = blockIdx.x * 256 + threadIdx.x;  // < 2048*128
  int m = idx >> 7, np = idx & 127;
  const float2* Pp = (const float2*)P;
  float2 s = {0.f, 0.f};
#pragma unroll
  for (int ks = 0; ks < SPLITK; ++ks) {
    float2 v = Pp[(size_t)(ks * MPAD + m) * 128 + np];
    s.x += v.x; s.y += v.y;
  }
  s.x += b1[2 * np]; s.y += b1[2 * np + 1];
  s.x = fmaxf(s.x, 0.f); s.y = fmaxf(s.y, 0.f);
  h1u[idx] = (uint)bf16r(s.x) | ((uint)bf16r(s.y) << 16);
}

// GEMM2 (64 rows x full N=256, K=256) + fused cls/reg heads
__global__ __launch_bounds__(256) void k_gemm2(const ushort* __restrict__ h1b,
                                               const ushort* __restrict__ w2t,
                                               const float* __restrict__ b2,
                                               const float* __restrict__ wcls,
                                               const float* __restrict__ bcls,
                                               const float* __restrict__ wreg,
                                               const float* __restrict__ breg,
                                               float* __restrict__ out) {
  __shared__ ushort As2[64 * 64];
  __shared__ ushort Bs2[256 * 64];
  __shared__ float Hs[64 * 257];
  int tid = threadIdx.x;
  int r0 = blockIdx.x * 64;
  int lane = tid & 63, wv = tid >> 6;
  int lm = lane & 15, quad = lane >> 4;
  int srow = tid >> 3, scol = (tid & 7) * 8;
  v4f acc[16];
#pragma unroll
  for (int j = 0; j < 16; ++j) acc[j] = (v4f){0.f, 0.f, 0.f, 0.f};
  for (int kt = 0; kt < 4; ++kt) {
    __syncthreads();
#pragma unroll
    for (int r = 0; r < 2; ++r)
      async16(h1b + (size_t)(r0 + srow + r * 32) * 256 + kt * 64 + scol,
              &As2[(srow + r * 32) * 64 + scol]);
#pragma unroll
    for (int r = 0; r < 8; ++r)
      async16(w2t + (size_t)(srow + r * 32) * 256 + kt * 64 + scol,
              &Bs2[(srow + r * 32) * 64 + scol]);
    __syncthreads();
#pragma unroll
    for (int kk = 0; kk < 64; kk += 32) {
      v8bf a = *(const v8bf*)&As2[(wv * 16 + lm) * 64 + kk + quad * 8];
#pragma unroll
      for (int j = 0; j < 16; ++j) {
        v8bf b = *(const v8bf*)&Bs2[(j * 16 + lm) * 64 + kk + quad * 8];
        acc[j] = __builtin_amdgcn_mfma_f32_16x16x32_bf16(a, b, acc[j], 0, 0, 0);
      }
    }
  }
#pragma unroll
  for (int j = 0; j < 16; ++j) {
    int nn = j * 16 + lm;
    float bb = b2[nn];
#pragma unroll
    for (int r = 0; r < 4; ++r) {
      int row = wv * 16 + quad * 4 + r;
      Hs[row * 257 + nn] = fmaxf(acc[j][r] + bb, 0.f);
    }
  }
  __syncthreads();
  for (int o = tid; o < 384; o += 256) {
    int hd = o >> 6, r = o & 63;
    int grow = r0 + r;
    float d = 0.f;
    if (hd < 2) {
      for (int k = 0; k < 256; ++k) d += Hs[r * 257 + k] * wcls[k * 2 + hd];
      d += bcls[hd];
      if (grow < NROI) out[grow * 2 + hd] = d;
    } else {
      int h4 = hd - 2;
      for (int k = 0; k < 256; ++k) d += Hs[r * 257 + k] * wreg[k * 4 + h4];
      d += breg[h4];
      if (grow < NROI) out[4000 + grow * 4 + h4] = d;
    }
  }
}

extern "C" void kernel_launch(void* const* d_in, const int* in_sizes, int n_in,
                              void* d_out, int out_size, void* d_ws, size_t ws_size,
                              hipStream_t stream) {
  const float* features = (const float*)d_in[0];
  const int* rois = (const int*)d_in[1];
  const float* w1 = (const float*)d_in[2];
  const float* b1 = (const float*)d_in[3];
  const float* w2 = (const float*)d_in[4];
  const float* b2 = (const float*)d_in[5];
  const float* wcls = (const float*)d_in[6];
  const float* bcls = (const float*)d_in[7];
  const float* wreg = (const float*)d_in[8];
  const float* breg = (const float*)d_in[9];
  char* ws = (char*)d_ws;
  ushort* ft  = (ushort*)(ws + 0);          // 57,802,752 B
  ushort* w1t = (ushort*)(ws + 57802752);   //  6,422,528 B
  ushort* w2t = (ushort*)(ws + 64225280);   //    131,072 B
  ushort* rf  = (ushort*)(ws + 64356352);   // 51,380,224 B (2048 rows)
  float*  P   = (float*)(ws + 115736576);   // 29,360,128 B
  ushort* h1b = (ushort*)(ws + 145096704);  //  1,048,576 B
  float* out = (float*)d_out;

  hipLaunchKernelGGL(k_transpose, dim3(882), dim3(128), 0, stream, features, ft);
  hipLaunchKernelGGL(k_w1perm, dim3(392), dim3(256), 0, stream, w1, (uint*)w1t);
  hipLaunchKernelGGL(k_w2t, dim3(256), dim3(256), 0, stream, w2, w2t);
  hipLaunchKernelGGL(k_pool, dim3(NROI), dim3(128), 0, stream, rois, (const uint*)ft, (uint*)rf);
  hipLaunchKernelGGL(k_gemm1, dim3(16, 2, SPLITK), dim3(256), 0, stream, rf, w1t, P);
  hipLaunchKernelGGL(k_reduce, dim3(1024), dim3(256), 0, stream, P, b1, (uint*)h1b);
  hipLaunchKernelGGL(k_gemm2, dim3(32), dim3(256), 0, stream, h1b, w2t, b2, wcls, bcls, wreg, breg, out);
}

// Round 2
// 461.745 us; speedup vs baseline: 1.9255x; 1.9255x over previous
//
#include <hip/hip_runtime.h>

typedef unsigned int uint;
typedef unsigned short ushort;
typedef __bf16 v8bf __attribute__((ext_vector_type(8)));
typedef float v4f __attribute__((ext_vector_type(4)));

#define CCH 256
#define HH 336
#define WW 336
#define HWSZ (HH*WW)
#define NROI 2000
#define KDIM 12544       // 49*256
#define MPAD 2048
#define SPLITK 14
#define KSP (KDIM/SPLITK)   // 896

__device__ __forceinline__ ushort bf16r(float f) {
  uint u = __float_as_uint(f);
  u += 0x7fffu + ((u >> 16) & 1u);   // RTNE
  return (ushort)(u >> 16);
}

typedef const __attribute__((address_space(1))) uint* gas_t;
typedef __attribute__((address_space(3))) uint* las_t;
__device__ __forceinline__ void async16(const void* g, void* l) {
  __builtin_amdgcn_global_load_lds((gas_t)g, (las_t)l, 16, 0, 0);
}

// features [256][336][336] fp32 -> ft [hw][c] bf16
__global__ __launch_bounds__(128) void k_transpose(const float* __restrict__ f,
                                                   ushort* __restrict__ ft) {
  int c8 = threadIdx.x & 31;      // channel-octet
  int hwo = threadIdx.x >> 5;     // 0..3
  int hw0 = blockIdx.x * 128;
  const float* fp = f + (size_t)c8 * 8 * HWSZ;
  for (int i = 0; i < 32; ++i) {
    int hw = hw0 + i * 4 + hwo;
    uint u[4];
#pragma unroll
    for (int j = 0; j < 4; ++j) {
      float a = fp[(size_t)(2 * j) * HWSZ + hw];
      float b = fp[(size_t)(2 * j + 1) * HWSZ + hw];
      u[j] = (uint)bf16r(a) | ((uint)bf16r(b) << 16);
    }
    *(uint4*)(ft + (size_t)hw * 256 + c8 * 8) = make_uint4(u[0], u[1], u[2], u[3]);
  }
}

// w1 [12544][256] fp32 (k = c*49+bin) -> w1t bf16 [n][k'] with k' = bin*256+c
__global__ __launch_bounds__(256) void k_w1perm(const float* __restrict__ w1,
                                                uint* __restrict__ w1t_u) {
  int bin = blockIdx.x % 49;
  int c0 = (blockIdx.x / 49) * 32;
  __shared__ ushort T[32][258];
  int n = threadIdx.x;
  for (int i = 0; i < 32; ++i)
    T[i][n] = bf16r(w1[(size_t)((c0 + i) * 49 + bin) * 256 + n]);
  __syncthreads();
  int cc = threadIdx.x & 15;
  int nb = threadIdx.x >> 4;
  for (int rep = 0; rep < 16; ++rep) {
    int nn = rep * 16 + nb;
    uint v = (uint)T[2 * cc][nn] | ((uint)T[2 * cc + 1][nn] << 16);
    w1t_u[(size_t)nn * (KDIM / 2) + bin * 128 + c0 / 2 + cc] = v;
  }
}

// w2 [256][256] -> w2t bf16 [n][k]
__global__ __launch_bounds__(256) void k_w2t(const float* __restrict__ w2,
                                             ushort* __restrict__ w2t) {
  int n = blockIdx.x, k = threadIdx.x;
  w2t[n * 256 + k] = bf16r(w2[k * 256 + n]);
}

// grid (NROI, 7): one wave per (ROI, bin-row); each lane = 4 channels (uint2).
__global__ __launch_bounds__(64) void k_pool(const int* __restrict__ rois,
                                             const uint2* __restrict__ ft2,
                                             uint2* __restrict__ rf2) {
  int n = blockIdx.x;
  int by = blockIdx.y;
  int t = threadIdx.x;            // 0..63 -> channels 4t..4t+3
  int x1 = rois[n * 4 + 0], y1 = rois[n * 4 + 1];
  int x2 = rois[n * 4 + 2], y2 = rois[n * 4 + 3];
  int Lw = x2 - x1 + 1, Lh = y2 - y1 + 1;
  int ylo = y1 + (by * Lh) / 7;
  int yhi = y1 + ((by + 1) * Lh + 6) / 7;
  uint ob = (uint)n * 3136;       // 6272 uints / 2
  for (int bx = 0; bx < 7; ++bx) {
    int xlo = x1 + (bx * Lw) / 7;
    int xhi = x1 + ((bx + 1) * Lw + 6) / 7;
    float a0 = 0.f, a1 = 0.f, a2 = 0.f, a3 = 0.f;
    for (int y = ylo; y < yhi; ++y) {
      const uint2* p = ft2 + (size_t)(y * WW + xlo) * 64 + t;
      for (int x = xlo; x < xhi; ++x) {
        uint2 u = *p; p += 64;
        a0 += __uint_as_float(u.x << 16);
        a1 += __uint_as_float(u.x & 0xffff0000u);
        a2 += __uint_as_float(u.y << 16);
        a3 += __uint_as_float(u.y & 0xffff0000u);
      }
    }
    float inv = 1.0f / (float)((yhi - ylo) * (xhi - xlo));
    uint2 o;
    o.x = (uint)bf16r(a0 * inv) | ((uint)bf16r(a1 * inv) << 16);
    o.y = (uint)bf16r(a2 * inv) | ((uint)bf16r(a3 * inv) << 16);
    rf2[ob + (uint)(by * 7 + bx) * 64 + t] = o;
  }
}

// NT GEMM: A=rf [2048][12544], B=w1t [256][12544], split-K -> P [14][2048][256] fp32
__global__ __launch_bounds__(256) void k_gemm1(const ushort* __restrict__ A,
                                               const ushort* __restrict__ B,
                                               float* __restrict__ P) {
  __shared__ ushort As[128 * 64];
  __shared__ ushort Bs[128 * 64];
  int m0 = blockIdx.x * 128;
  int n0 = blockIdx.y * 128;
  int ks = blockIdx.z;
  int k0 = ks * KSP;
  int tid = threadIdx.x;
  int lane = tid & 63, wv = tid >> 6;
  int wm = wv >> 1, wn = wv & 1;
  int lm = lane & 15, quad = lane >> 4;
  int srow = tid >> 3, scol = (tid & 7) * 8;
  v4f acc[4][4];
#pragma unroll
  for (int i = 0; i < 4; ++i)
#pragma unroll
    for (int j = 0; j < 4; ++j) acc[i][j] = (v4f){0.f, 0.f, 0.f, 0.f};
  const ushort* Ab = A + (size_t)(m0 + srow) * KDIM + k0 + scol;
  const ushort* Bb = B + (size_t)(n0 + srow) * KDIM + k0 + scol;
  for (int kt = 0; kt < KSP / 64; ++kt) {
    __syncthreads();
#pragma unroll
    for (int r = 0; r < 4; ++r)
      async16(Ab + (size_t)(r * 32) * KDIM + kt * 64, &As[(srow + r * 32) * 64 + scol]);
#pragma unroll
    for (int r = 0; r < 4; ++r)
      async16(Bb + (size_t)(r * 32) * KDIM + kt * 64, &Bs[(srow + r * 32) * 64 + scol]);
    __syncthreads();
#pragma unroll
    for (int kk = 0; kk < 64; kk += 32) {
      v8bf a[4], b[4];
#pragma unroll
      for (int i = 0; i < 4; ++i)
        a[i] = *(const v8bf*)&As[(wm * 64 + i * 16 + lm) * 64 + kk + quad * 8];
#pragma unroll
      for (int j = 0; j < 4; ++j)
        b[j] = *(const v8bf*)&Bs[(wn * 64 + j * 16 + lm) * 64 + kk + quad * 8];
#pragma unroll
      for (int i = 0; i < 4; ++i)
#pragma unroll
        for (int j = 0; j < 4; ++j)
          acc[i][j] = __builtin_amdgcn_mfma_f32_16x16x32_bf16(a[i], b[j], acc[i][j], 0, 0, 0);
    }
  }
  float* Pb = P + (size_t)ks * MPAD * 256;
#pragma unroll
  for (int i = 0; i < 4; ++i)
#pragma unroll
    for (int j = 0; j < 4; ++j) {
      int row = m0 + wm * 64 + i * 16 + quad * 4;
      int col = n0 + wn * 64 + j * 16 + lm;
#pragma unroll
      for (int r = 0; r < 4; ++r)
        Pb[(size_t)(row + r) * 256 + col] = acc[i][j][r];
    }
}

// sum split-K partials + bias + relu -> h1 bf16 [2048][256]
__global__ __launch_bounds__(256) void k_reduce(const float* __restrict__ P,
                                                const float* __restrict__ b1,
                                                uint* __restrict__ h1u) {
  int idx = blockIdx.x * 256 + threadIdx.x;  // < 2048*128
  int m = idx >> 7, np = idx & 127;
  const float2* Pp = (const float2*)P;
  float2 s = {0.f, 0.f};
#pragma unroll
  for (int ks = 0; ks < SPLITK; ++ks) {
    float2 v = Pp[(size_t)(ks * MPAD + m) * 128 + np];
    s.x += v.x; s.y += v.y;
  }
  s.x += b1[2 * np]; s.y += b1[2 * np + 1];
  s.x = fmaxf(s.x, 0.f); s.y = fmaxf(s.y, 0.f);
  h1u[idx] = (uint)bf16r(s.x) | ((uint)bf16r(s.y) << 16);
}

// GEMM2 (64 rows x full N=256, K=256) + fused cls/reg heads
__global__ __launch_bounds__(256) void k_gemm2(const ushort* __restrict__ h1b,
                                               const ushort* __restrict__ w2t,
                                               const float* __restrict__ b2,
                                               const float* __restrict__ wcls,
                                               const float* __restrict__ bcls,
                                               const float* __restrict__ wreg,
                                               const float* __restrict__ breg,
                                               float* __restrict__ out) {
  __shared__ ushort As2[64 * 64];
  __shared__ ushort Bs2[256 * 64];
  __shared__ float Hs[64 * 257];
  int tid = threadIdx.x;
  int r0 = blockIdx.x * 64;
  int lane = tid & 63, wv = tid >> 6;
  int lm = lane & 15, quad = lane >> 4;
  int srow = tid >> 3, scol = (tid & 7) * 8;
  v4f acc[16];
#pragma unroll
  for (int j = 0; j < 16; ++j) acc[j] = (v4f){0.f, 0.f, 0.f, 0.f};
  for (int kt = 0; kt < 4; ++kt) {
    __syncthreads();
#pragma unroll
    for (int r = 0; r < 2; ++r)
      async16(h1b + (size_t)(r0 + srow + r * 32) * 256 + kt * 64 + scol,
              &As2[(srow + r * 32) * 64 + scol]);
#pragma unroll
    for (int r = 0; r < 8; ++r)
      async16(w2t + (size_t)(srow + r * 32) * 256 + kt * 64 + scol,
              &Bs2[(srow + r * 32) * 64 + scol]);
    __syncthreads();
#pragma unroll
    for (int kk = 0; kk < 64; kk += 32) {
      v8bf a = *(const v8bf*)&As2[(wv * 16 + lm) * 64 + kk + quad * 8];
#pragma unroll
      for (int j = 0; j < 16; ++j) {
        v8bf b = *(const v8bf*)&Bs2[(j * 16 + lm) * 64 + kk + quad * 8];
        acc[j] = __builtin_amdgcn_mfma_f32_16x16x32_bf16(a, b, acc[j], 0, 0, 0);
      }
    }
  }
#pragma unroll
  for (int j = 0; j < 16; ++j) {
    int nn = j * 16 + lm;
    float bb = b2[nn];
#pragma unroll
    for (int r = 0; r < 4; ++r) {
      int row = wv * 16 + quad * 4 + r;
      Hs[row * 257 + nn] = fmaxf(acc[j][r] + bb, 0.f);
    }
  }
  __syncthreads();
  for (int o = tid; o < 384; o += 256) {
    int hd = o >> 6, r = o & 63;
    int grow = r0 + r;
    float d = 0.f;
    if (hd < 2) {
      for (int k = 0; k < 256; ++k) d += Hs[r * 257 + k] * wcls[k * 2 + hd];
      d += bcls[hd];
      if (grow < NROI) out[grow * 2 + hd] = d;
    } else {
      int h4 = hd - 2;
      for (int k = 0; k < 256; ++k) d += Hs[r * 257 + k] * wreg[k * 4 + h4];
      d += breg[h4];
      if (grow < NROI) out[4000 + grow * 4 + h4] = d;
    }
  }
}

extern "C" void kernel_launch(void* const* d_in, const int* in_sizes, int n_in,
                              void* d_out, int out_size, void* d_ws, size_t ws_size,
                              hipStream_t stream) {
  const float* features = (const float*)d_in[0];
  const int* rois = (const int*)d_in[1];
  const float* w1 = (const float*)d_in[2];
  const float* b1 = (const float*)d_in[3];
  const float* w2 = (const float*)d_in[4];
  const float* b2 = (const float*)d_in[5];
  const float* wcls = (const float*)d_in[6];
  const float* bcls = (const float*)d_in[7];
  const float* wreg = (const float*)d_in[8];
  const float* breg = (const float*)d_in[9];
  char* ws = (char*)d_ws;
  ushort* ft  = (ushort*)(ws + 0);          // 57,802,752 B
  ushort* w1t = (ushort*)(ws + 57802752);   //  6,422,528 B
  ushort* w2t = (ushort*)(ws + 64225280);   //    131,072 B
  ushort* rf  = (ushort*)(ws + 64356352);   // 51,380,224 B (2048 rows)
  float*  P   = (float*)(ws + 115736576);   // 29,360,128 B
  ushort* h1b = (ushort*)(ws + 145096704);  //  1,048,576 B
  float* out = (float*)d_out;

  hipLaunchKernelGGL(k_transpose, dim3(882), dim3(128), 0, stream, features, ft);
  hipLaunchKernelGGL(k_w1perm, dim3(392), dim3(256), 0, stream, w1, (uint*)w1t);
  hipLaunchKernelGGL(k_w2t, dim3(256), dim3(256), 0, stream, w2, w2t);
  hipLaunchKernelGGL(k_pool, dim3(NROI, 7), dim3(64), 0, stream, rois,
                     (const uint2*)ft, (uint2*)rf);
  hipLaunchKernelGGL(k_gemm1, dim3(16, 2, SPLITK), dim3(256), 0, stream, rf, w1t, P);
  hipLaunchKernelGGL(k_reduce, dim3(1024), dim3(256), 0, stream, P, b1, (uint*)h1b);
  hipLaunchKernelGGL(k_gemm2, dim3(32), dim3(256), 0, stream, h1b, w2t, b2, wcls, bcls, wreg, breg, out);
}

// Round 3
// 383.628 us; speedup vs baseline: 2.3175x; 1.2036x over previous
//
#include <hip/hip_runtime.h>

typedef unsigned int uint;
typedef unsigned short ushort;
typedef __bf16 v8bf __attribute__((ext_vector_type(8)));
typedef float v4f __attribute__((ext_vector_type(4)));

#define CCH 256
#define HH 336
#define WW 336
#define HWSZ (HH*WW)
#define NROI 2000
#define KDIM 12544       // 49*256
#define MPAD 2048
#define SPLITK 14
#define KSP (KDIM/SPLITK)   // 896

__device__ __forceinline__ ushort bf16r(float f) {
  uint u = __float_as_uint(f);
  u += 0x7fffu + ((u >> 16) & 1u);   // RTNE
  return (ushort)(u >> 16);
}
__device__ __forceinline__ uint packbf(float a, float b) {
  return (uint)bf16r(a) | ((uint)bf16r(b) << 16);
}

typedef const __attribute__((address_space(1))) uint* gas_t;
typedef __attribute__((address_space(3))) uint* las_t;
__device__ __forceinline__ void async16(const void* g, void* l) {
  __builtin_amdgcn_global_load_lds((gas_t)g, (las_t)l, 16, 0, 0);
}

// features [256][336][336] fp32 -> ft [hw][c] bf16, LDS-tiled.
// Block: 256 thr, tile 64 hw x 256 c. Phase1 coalesced reads (lane=hw),
// phase2 ds_read_b128 + 16B coalesced writes. Row pad 132 uints.
__global__ __launch_bounds__(256) void k_transpose(const float* __restrict__ f,
                                                   uint* __restrict__ ftu) {
  __shared__ uint T[64 * 132];
  int tid = threadIdx.x;
  int hw0 = blockIdx.x * 64;
  int hwl = tid & 63;
  int cq = tid >> 6;              // 0..3
  int hw = hw0 + hwl;
#pragma unroll 4
  for (int it = 0; it < 32; ++it) {
    int c = it * 8 + cq * 2;
    float a = f[(size_t)c * HWSZ + hw];
    float b = f[(size_t)(c + 1) * HWSZ + hw];
    T[hwl * 132 + it * 4 + cq] = packbf(a, b);
  }
  __syncthreads();
  int co = tid & 31, r = tid >> 5;   // 8 rows per iter
#pragma unroll
  for (int i = 0; i < 8; ++i) {
    int hwr = i * 8 + r;
    uint4 v = *(const uint4*)&T[hwr * 132 + co * 4];
    *(uint4*)(ftu + (size_t)(hw0 + hwr) * 128 + co * 4) = v;
  }
}

// w1 [12544][256] fp32 (k = c*49+bin) -> w1t bf16 [n][k'] with k' = bin*256+c
__global__ __launch_bounds__(256) void k_w1perm(const float* __restrict__ w1,
                                                uint* __restrict__ w1t_u) {
  int bin = blockIdx.x % 49;
  int c0 = (blockIdx.x / 49) * 32;
  __shared__ ushort T[32][258];
  int n = threadIdx.x;
  for (int i = 0; i < 32; ++i)
    T[i][n] = bf16r(w1[(size_t)((c0 + i) * 49 + bin) * 256 + n]);
  __syncthreads();
  int cc = threadIdx.x & 15;
  int nb = threadIdx.x >> 4;
  for (int rep = 0; rep < 16; ++rep) {
    int nn = rep * 16 + nb;
    uint v = (uint)T[2 * cc][nn] | ((uint)T[2 * cc + 1][nn] << 16);
    w1t_u[(size_t)nn * (KDIM / 2) + bin * 128 + c0 / 2 + cc] = v;
  }
}

// w2 [256][256] -> w2t bf16 [n][k]
__global__ __launch_bounds__(256) void k_w2t(const float* __restrict__ w2,
                                             ushort* __restrict__ w2t) {
  int n = blockIdx.x, k = threadIdx.x;
  w2t[n * 256 + k] = bf16r(w2[k * 256 + n]);
}

// grid (NROI, 7): one wave per (ROI, bin-row).
// lane: co = t&31 (channel-octet, uint4 16B), par = t>>5 (pixel parity).
// Row-walk: each pixel loaded once; bin membership via wave-uniform branches.
#define ACC8(u, xx) do {                                                    \
  float v0 = __uint_as_float((u).x << 16);                                  \
  float v1 = __uint_as_float((u).x & 0xffff0000u);                          \
  float v2 = __uint_as_float((u).y << 16);                                  \
  float v3 = __uint_as_float((u).y & 0xffff0000u);                          \
  float v4 = __uint_as_float((u).z << 16);                                  \
  float v5 = __uint_as_float((u).z & 0xffff0000u);                          \
  float v6 = __uint_as_float((u).w << 16);                                  \
  float v7 = __uint_as_float((u).w & 0xffff0000u);                          \
  _Pragma("unroll")                                                         \
  for (int b = 0; b < 7; ++b)                                               \
    if ((xx) >= xlo[b] && (xx) < xhi[b]) {                                  \
      acc[b][0] += v0; acc[b][1] += v1; acc[b][2] += v2; acc[b][3] += v3;   \
      acc[b][4] += v4; acc[b][5] += v5; acc[b][6] += v6; acc[b][7] += v7;   \
    }                                                                       \
} while (0)

__global__ __launch_bounds__(64) void k_pool(const int* __restrict__ rois,
                                             const uint4* __restrict__ ft4,
                                             uint4* __restrict__ rf4) {
  int n = blockIdx.x;
  int by = blockIdx.y;
  int t = threadIdx.x;
  int co = t & 31, par = t >> 5;
  int x1 = rois[n * 4 + 0], y1 = rois[n * 4 + 1];
  int x2 = rois[n * 4 + 2], y2 = rois[n * 4 + 3];
  int Lw = x2 - x1 + 1, Lh = y2 - y1 + 1;
  int ylo = y1 + (by * Lh) / 7;
  int yhi = y1 + ((by + 1) * Lh + 6) / 7;
  int xlo[7], xhi[7];
#pragma unroll
  for (int b = 0; b < 7; ++b) {
    xlo[b] = x1 + (b * Lw) / 7;
    xhi[b] = x1 + ((b + 1) * Lw + 6) / 7;
  }
  float acc[7][8];
#pragma unroll
  for (int b = 0; b < 7; ++b)
#pragma unroll
    for (int j = 0; j < 8; ++j) acc[b][j] = 0.f;
  int xf = x1 + par;
  int cnt = (x2 - xf) / 2 + 1;     // Lw >= 5 so cnt >= 2
  for (int y = ylo; y < yhi; ++y) {
    const uint4* p = ft4 + (size_t)(y * WW + xf) * 32 + co;
    int x = xf, rem = cnt;
    while (rem >= 4) {
      uint4 u0 = p[0], u1 = p[64], u2 = p[128], u3 = p[192];
      p += 256;
      ACC8(u0, x); ACC8(u1, x + 2); ACC8(u2, x + 4); ACC8(u3, x + 6);
      x += 8; rem -= 4;
    }
    while (rem > 0) {
      uint4 u = p[0]; p += 64;
      ACC8(u, x); x += 2; --rem;
    }
  }
#pragma unroll
  for (int b = 0; b < 7; ++b)
#pragma unroll
    for (int j = 0; j < 8; ++j)
      acc[b][j] += __shfl_xor(acc[b][j], 32, 64);
  if (t < 32) {
    uint ob = (uint)n * 1568 + (uint)by * 224 + co;
    int rh = yhi - ylo;
#pragma unroll
    for (int b = 0; b < 7; ++b) {
      float inv = 1.0f / (float)(rh * (xhi[b] - xlo[b]));
      uint4 o;
      o.x = packbf(acc[b][0] * inv, acc[b][1] * inv);
      o.y = packbf(acc[b][2] * inv, acc[b][3] * inv);
      o.z = packbf(acc[b][4] * inv, acc[b][5] * inv);
      o.w = packbf(acc[b][6] * inv, acc[b][7] * inv);
      rf4[ob + b * 32] = o;
    }
  }
}

// NT GEMM: A=rf [2048][12544], B=w1t [256][12544], split-K -> P [14][2048][256] fp32
__global__ __launch_bounds__(256) void k_gemm1(const ushort* __restrict__ A,
                                               const ushort* __restrict__ B,
                                               float* __restrict__ P) {
  __shared__ ushort As[128 * 64];
  __shared__ ushort Bs[128 * 64];
  int m0 = blockIdx.x * 128;
  int n0 = blockIdx.y * 128;
  int ks = blockIdx.z;
  int k0 = ks * KSP;
  int tid = threadIdx.x;
  int lane = tid & 63, wv = tid >> 6;
  int wm = wv >> 1, wn = wv & 1;
  int lm = lane & 15, quad = lane >> 4;
  int srow = tid >> 3, scol = (tid & 7) * 8;
  v4f acc[4][4];
#pragma unroll
  for (int i = 0; i < 4; ++i)
#pragma unroll
    for (int j = 0; j < 4; ++j) acc[i][j] = (v4f){0.f, 0.f, 0.f, 0.f};
  const ushort* Ab = A + (size_t)(m0 + srow) * KDIM + k0 + scol;
  const ushort* Bb = B + (size_t)(n0 + srow) * KDIM + k0 + scol;
  for (int kt = 0; kt < KSP / 64; ++kt) {
    __syncthreads();
#pragma unroll
    for (int r = 0; r < 4; ++r)
      async16(Ab + (size_t)(r * 32) * KDIM + kt * 64, &As[(srow + r * 32) * 64 + scol]);
#pragma unroll
    for (int r = 0; r < 4; ++r)
      async16(Bb + (size_t)(r * 32) * KDIM + kt * 64, &Bs[(srow + r * 32) * 64 + scol]);
    __syncthreads();
#pragma unroll
    for (int kk = 0; kk < 64; kk += 32) {
      v8bf a[4], b[4];
#pragma unroll
      for (int i = 0; i < 4; ++i)
        a[i] = *(const v8bf*)&As[(wm * 64 + i * 16 + lm) * 64 + kk + quad * 8];
#pragma unroll
      for (int j = 0; j < 4; ++j)
        b[j] = *(const v8bf*)&Bs[(wn * 64 + j * 16 + lm) * 64 + kk + quad * 8];
#pragma unroll
      for (int i = 0; i < 4; ++i)
#pragma unroll
        for (int j = 0; j < 4; ++j)
          acc[i][j] = __builtin_amdgcn_mfma_f32_16x16x32_bf16(a[i], b[j], acc[i][j], 0, 0, 0);
    }
  }
  float* Pb = P + (size_t)ks * MPAD * 256;
#pragma unroll
  for (int i = 0; i < 4; ++i)
#pragma unroll
    for (int j = 0; j < 4; ++j) {
      int row = m0 + wm * 64 + i * 16 + quad * 4;
      int col = n0 + wn * 64 + j * 16 + lm;
#pragma unroll
      for (int r = 0; r < 4; ++r)
        Pb[(size_t)(row + r) * 256 + col] = acc[i][j][r];
    }
}

// sum split-K partials + bias + relu -> h1 bf16 [2048][256]
__global__ __launch_bounds__(256) void k_reduce(const float* __restrict__ P,
                                                const float* __restrict__ b1,
                                                uint* __restrict__ h1u) {
  int idx = blockIdx.x * 256 + threadIdx.x;  // < 2048*128
  int m = idx >> 7, np = idx & 127;
  const float2* Pp = (const float2*)P;
  float2 s = {0.f, 0.f};
#pragma unroll
  for (int ks = 0; ks < SPLITK; ++ks) {
    float2 v = Pp[(size_t)(ks * MPAD + m) * 128 + np];
    s.x += v.x; s.y += v.y;
  }
  s.x += b1[2 * np]; s.y += b1[2 * np + 1];
  s.x = fmaxf(s.x, 0.f); s.y = fmaxf(s.y, 0.f);
  h1u[idx] = packbf(s.x, s.y);
}

// GEMM2 (64 rows x full N=256, K=256) + fused cls/reg heads
__global__ __launch_bounds__(256) void k_gemm2(const ushort* __restrict__ h1b,
                                               const ushort* __restrict__ w2t,
                                               const float* __restrict__ b2,
                                               const float* __restrict__ wcls,
                                               const float* __restrict__ bcls,
                                               const float* __restrict__ wreg,
                                               const float* __restrict__ breg,
                                               float* __restrict__ out) {
  __shared__ ushort As2[64 * 64];
  __shared__ ushort Bs2[256 * 64];
  __shared__ float Hs[64 * 257];
  int tid = threadIdx.x;
  int r0 = blockIdx.x * 64;
  int lane = tid & 63, wv = tid >> 6;
  int lm = lane & 15, quad = lane >> 4;
  int srow = tid >> 3, scol = (tid & 7) * 8;
  v4f acc[16];
#pragma unroll
  for (int j = 0; j < 16; ++j) acc[j] = (v4f){0.f, 0.f, 0.f, 0.f};
  for (int kt = 0; kt < 4; ++kt) {
    __syncthreads();
#pragma unroll
    for (int r = 0; r < 2; ++r)
      async16(h1b + (size_t)(r0 + srow + r * 32) * 256 + kt * 64 + scol,
              &As2[(srow + r * 32) * 64 + scol]);
#pragma unroll
    for (int r = 0; r < 8; ++r)
      async16(w2t + (size_t)(srow + r * 32) * 256 + kt * 64 + scol,
              &Bs2[(srow + r * 32) * 64 + scol]);
    __syncthreads();
#pragma unroll
    for (int kk = 0; kk < 64; kk += 32) {
      v8bf a = *(const v8bf*)&As2[(wv * 16 + lm) * 64 + kk + quad * 8];
#pragma unroll
      for (int j = 0; j < 16; ++j) {
        v8bf b = *(const v8bf*)&Bs2[(j * 16 + lm) * 64 + kk + quad * 8];
        acc[j] = __builtin_amdgcn_mfma_f32_16x16x32_bf16(a, b, acc[j], 0, 0, 0);
      }
    }
  }
#pragma unroll
  for (int j = 0; j < 16; ++j) {
    int nn = j * 16 + lm;
    float bb = b2[nn];
#pragma unroll
    for (int r = 0; r < 4; ++r) {
      int row = wv * 16 + quad * 4 + r;
      Hs[row * 257 + nn] = fmaxf(acc[j][r] + bb, 0.f);
    }
  }
  __syncthreads();
  for (int o = tid; o < 384; o += 256) {
    int hd = o >> 6, r = o & 63;
    int grow = r0 + r;
    float d = 0.f;
    if (hd < 2) {
      for (int k = 0; k < 256; ++k) d += Hs[r * 257 + k] * wcls[k * 2 + hd];
      d += bcls[hd];
      if (grow < NROI) out[grow * 2 + hd] = d;
    } else {
      int h4 = hd - 2;
      for (int k = 0; k < 256; ++k) d += Hs[r * 257 + k] * wreg[k * 4 + h4];
      d += breg[h4];
      if (grow < NROI) out[4000 + grow * 4 + h4] = d;
    }
  }
}

extern "C" void kernel_launch(void* const* d_in, const int* in_sizes, int n_in,
                              void* d_out, int out_size, void* d_ws, size_t ws_size,
                              hipStream_t stream) {
  const float* features = (const float*)d_in[0];
  const int* rois = (const int*)d_in[1];
  const float* w1 = (const float*)d_in[2];
  const float* b1 = (const float*)d_in[3];
  const float* w2 = (const float*)d_in[4];
  const float* b2 = (const float*)d_in[5];
  const float* wcls = (const float*)d_in[6];
  const float* bcls = (const float*)d_in[7];
  const float* wreg = (const float*)d_in[8];
  const float* breg = (const float*)d_in[9];
  char* ws = (char*)d_ws;
  ushort* ft  = (ushort*)(ws + 0);          // 57,802,752 B
  ushort* w1t = (ushort*)(ws + 57802752);   //  6,422,528 B
  ushort* w2t = (ushort*)(ws + 64225280);   //    131,072 B
  ushort* rf  = (ushort*)(ws + 64356352);   // 51,380,224 B (2048 rows)
  float*  P   = (float*)(ws + 115736576);   // 29,360,128 B
  ushort* h1b = (ushort*)(ws + 145096704);  //  1,048,576 B
  float* out = (float*)d_out;

  hipLaunchKernelGGL(k_transpose, dim3(HWSZ / 64), dim3(256), 0, stream,
                     features, (uint*)ft);
  hipLaunchKernelGGL(k_w1perm, dim3(392), dim3(256), 0, stream, w1, (uint*)w1t);
  hipLaunchKernelGGL(k_w2t, dim3(256), dim3(256), 0, stream, w2, w2t);
  hipLaunchKernelGGL(k_pool, dim3(NROI, 7), dim3(64), 0, stream, rois,
                     (const uint4*)ft, (uint4*)rf);
  hipLaunchKernelGGL(k_gemm1, dim3(16, 2, SPLITK), dim3(256), 0, stream, rf, w1t, P);
  hipLaunchKernelGGL(k_reduce, dim3(1024), dim3(256), 0, stream, P, b1, (uint*)h1b);
  hipLaunchKernelGGL(k_gemm2, dim3(32), dim3(256), 0, stream, h1b, w2t, b2, wcls, bcls, wreg, breg, out);
}